// Round 1
// 1191.607 us; speedup vs baseline: 1.0464x; 1.0464x over previous
//
#include <hip/hip_runtime.h>
#include <hip/hip_bf16.h>
#include <stdint.h>

#define T_TOK 8192
#define H     1024
#define HF    4096
#define NE    8
#define NPAIR (2 * T_TOK)

typedef __bf16 bf16x8 __attribute__((ext_vector_type(8)));
typedef float  floatx4 __attribute__((ext_vector_type(4)));

typedef const __attribute__((address_space(1))) uint32_t g_u32;
typedef __attribute__((address_space(3))) uint32_t l_u32;

__device__ __forceinline__ void async_ld16(const void* g, void* l) {
  // LDS dest = wave-uniform base + lane*16; per-lane global address
  __builtin_amdgcn_global_load_lds((g_u32*)g, (l_u32*)l, 16, 0, 0);
}

__device__ __forceinline__ unsigned short f2bf(float f) {
  union { float f; uint32_t u; } v; v.f = f;
  uint32_t r = (v.u + 0x7FFFu + ((v.u >> 16) & 1u)) >> 16;
  return (unsigned short)r;
}

// ---------------- init: zero counts ----------------
__global__ void k_init(int* counts) {
  if (threadIdx.x < NE) counts[threadIdx.x] = 0;
}

// ---------------- router: one wave per token ----------------
__global__ __launch_bounds__(256) void k_router(const float* __restrict__ x,
                                                const float* __restrict__ gw,
                                                int* counts, int* topk_e, float* topk_w) {
  int wave = threadIdx.x >> 6, lane = threadIdx.x & 63;
  int t = blockIdx.x * 4 + wave;
  float acc[NE];
#pragma unroll
  for (int e = 0; e < NE; e++) acc[e] = 0.f;
  const float* xr = x + (size_t)t * H;
  for (int k = lane; k < H; k += 64) {
    float xv = xr[k];
    const float* g = gw + (size_t)k * NE;
#pragma unroll
    for (int e = 0; e < NE; e++) acc[e] += xv * g[e];
  }
#pragma unroll
  for (int off = 32; off > 0; off >>= 1) {
#pragma unroll
    for (int e = 0; e < NE; e++) acc[e] += __shfl_xor(acc[e], off, 64);
  }
  if (lane == 0) {
    int e1 = 0;
#pragma unroll
    for (int e = 1; e < NE; e++) if (acc[e] > acc[e1]) e1 = e;
    int e2 = (e1 == 0) ? 1 : 0;
#pragma unroll
    for (int e = 0; e < NE; e++) if (e != e1 && acc[e] > acc[e2]) e2 = e;
    // renormalized top-2 softmax weights: w1 = p1/(p1+p2) = 1/(1+exp(l2-l1))
    float w1 = 1.f / (1.f + expf(acc[e2] - acc[e1]));
    topk_e[2 * t] = e1; topk_e[2 * t + 1] = e2;
    topk_w[2 * t] = w1; topk_w[2 * t + 1] = 1.f - w1;
    atomicAdd(&counts[e1], 1);
    atomicAdd(&counts[e2], 1);
  }
}

// ---------------- scan: offsets + zero cursors ----------------
__global__ void k_scan(const int* counts, int* offsets, int* cursors) {
  if (threadIdx.x == 0) {
    int s = 0;
    for (int e = 0; e < NE; e++) { offsets[e] = s; s += counts[e]; cursors[e] = 0; }
    offsets[NE] = s;
  }
}

// ---------------- fill: slot assignment + gather x -> bf16 packed A ----------------
__global__ __launch_bounds__(256) void k_fill(const float* __restrict__ x,
                                              const int* __restrict__ topk_e,
                                              const float* __restrict__ topk_w,
                                              const int* __restrict__ offsets, int* cursors,
                                              int* tok_slot, float* row_weight,
                                              unsigned short* __restrict__ A_pack) {
  int wave = threadIdx.x >> 6, lane = threadIdx.x & 63;
  int t = blockIdx.x * 4 + wave;
  int s1 = 0, s2 = 0;
  if (lane == 0) {
    int e1 = topk_e[2 * t], e2 = topk_e[2 * t + 1];
    s1 = offsets[e1] + atomicAdd(&cursors[e1], 1);
    s2 = offsets[e2] + atomicAdd(&cursors[e2], 1);
    tok_slot[2 * t] = s1; tok_slot[2 * t + 1] = s2;
    row_weight[s1] = topk_w[2 * t];
    row_weight[s2] = topk_w[2 * t + 1];
  }
  s1 = __shfl(s1, 0, 64);
  s2 = __shfl(s2, 0, 64);
  const float* xr = x + (size_t)t * H;
  unsigned short* d1 = A_pack + (size_t)s1 * H;
  unsigned short* d2 = A_pack + (size_t)s2 * H;
  for (int k = lane * 4; k < H; k += 256) {
    float4 v = *(const float4*)(xr + k);
    ushort4 b;
    b.x = f2bf(v.x); b.y = f2bf(v.y); b.z = f2bf(v.z); b.w = f2bf(v.w);
    *(ushort4*)(d1 + k) = b;
    *(ushort4*)(d2 + k) = b;
  }
}

// ---------------- transpose + cvt: [E][K][N] f32 -> [E][N][K] bf16 ----------------
__global__ __launch_bounds__(256) void k_transpose_cvt(const float* __restrict__ src,
                                                       unsigned short* __restrict__ dst,
                                                       int K, int N) {
  __shared__ unsigned short tile[64][65];
  int e = blockIdx.z;
  int k0 = blockIdx.x * 64, n0 = blockIdx.y * 64;
  const float* S = src + (size_t)e * K * N;
  unsigned short* D = dst + (size_t)e * N * K;
  int tr = threadIdx.x >> 4;
  int tc = (threadIdx.x & 15) * 4;
#pragma unroll
  for (int rr = 0; rr < 64; rr += 16) {
    float4 v = *(const float4*)(S + (size_t)(k0 + tr + rr) * N + n0 + tc);
    tile[tr + rr][tc + 0] = f2bf(v.x);
    tile[tr + rr][tc + 1] = f2bf(v.y);
    tile[tr + rr][tc + 2] = f2bf(v.z);
    tile[tr + rr][tc + 3] = f2bf(v.w);
  }
  __syncthreads();
#pragma unroll
  for (int rr = 0; rr < 64; rr += 16) {
    int i = tr + rr;
    ushort4 o;
    o.x = tile[tc + 0][i]; o.y = tile[tc + 1][i];
    o.z = tile[tc + 2][i]; o.w = tile[tc + 3][i];
    *(ushort4*)(D + (size_t)(n0 + i) * K + k0 + tc) = o;
  }
}

// ---------------- GEMM: 128x128 tile, BK=32, 4 waves, mfma_f32_16x16x32_bf16 ----------------
// v2 changes vs baseline:
//  * 2-phase double-buffered LDS: STAGE(next) issued BEFORE compute(cur); ONE
//    __syncthreads() per K-step (compiler's vmcnt(0)+lgkmcnt(0) drain before s_barrier
//    now overlaps the stage latency with this wave's own ds_read+MFMA).
//  * quad swizzle (row&3) -> ((row>>1)&3): ds_read_b128 conflicts 4-way -> 2-way (free).
//    Same XOR applied on DMA global source and LDS fragment read (both-sides rule).
//  * XCD-aware bijective chunking over the ACTIVE sub-grid (NX x ceil(cnt/128)),
//    m-fastest decomposition: each XCD keeps its B n-panels L2-resident.
// SECOND=false: epilogue relu^2 * row_weight -> hidden bf16
// SECOND=true : epilogue -> out_slot[p][col] fp32 (combined later; no atomics)
template <int KD, bool SECOND>
__global__ __launch_bounds__(256) void k_gemm(const unsigned short* __restrict__ A,
                                              const unsigned short* __restrict__ BT,
                                              const int* __restrict__ counts,
                                              const int* __restrict__ offsets,
                                              const float* __restrict__ row_weight,
                                              unsigned short* __restrict__ hidden,
                                              float* __restrict__ out_slot, int Nd) {
  int e = blockIdx.z;
  int cnt = counts[e];
  int nact = (cnt + 127) >> 7;               // active m-blocks for this expert
  int NX = gridDim.x;
  int bid = blockIdx.y * NX + blockIdx.x;
  int nwg_a = NX * nact;
  if (bid >= nwg_a) return;                  // dead padding blocks
  // m204 bijective XCD chunk swizzle over the active sub-grid
  int xcd = bid & 7, loc = bid >> 3;
  int q8 = nwg_a >> 3, r8 = nwg_a & 7;
  int swz = (xcd < r8 ? xcd * (q8 + 1) : r8 * (q8 + 1) + (xcd - r8) * q8) + loc;
  int by = swz % nact;                       // m fastest within an XCD chunk ->
  int bx = swz / nact;                       // B n-panel stays resident in that XCD's L2
  int m0 = by * 128;
  int moff = offsets[e];
  int n0 = bx * 128;

  __shared__ __align__(16) unsigned short As[2][128 * 32];
  __shared__ __align__(16) unsigned short Bs[2][128 * 32];

  int tid = threadIdx.x, wave = tid >> 6, lane = tid & 63;
  int wm = wave & 1, wn = wave >> 1;

  floatx4 acc[4][4] = {};

  const unsigned short* Ae = A + (size_t)(moff + m0) * KD;
  const unsigned short* Be = BT + (size_t)e * Nd * KD + (size_t)n0 * KD;

  // stage one 128x32 A-tile + B-tile into buffer `buf` at k-offset k0s
  auto stage = [&](int k0s, int buf) {
#pragma unroll
    for (int s = 0; s < 2; s++) {
      int cgrp = s * 4 + wave;          // 8 chunk-groups of 64 slots
      int slot = cgrp * 64 + lane;      // LDS 16B-slot index 0..511
      int row = slot >> 2;              // 4 consecutive lanes -> same row
      int qs = slot & 3;                // LDS k-quad
      int qg = qs ^ ((row >> 1) & 3);   // global k-quad (xor swizzle, stays in 64B line)
      const unsigned short* ga = Ae + (size_t)row * KD + k0s + qg * 8;
      const unsigned short* gb = Be + (size_t)row * KD + k0s + qg * 8;
      async_ld16(ga, (void*)(As[buf] + cgrp * 512));
      async_ld16(gb, (void*)(Bs[buf] + cgrp * 512));
    }
  };

  stage(0, 0);
  __syncthreads();                       // drain prologue stage
  int cur = 0;
  for (int k0 = 0; k0 < KD; k0 += 32) {
    if (k0 + 32 < KD) stage(k0 + 32, cur ^ 1);   // prefetch next tile (overlaps compute)

    int q = lane >> 4, l15 = lane & 15;
    bf16x8 aF[4], bF[4];
#pragma unroll
    for (int i = 0; i < 4; i++) {
      int r = wm * 64 + i * 16 + l15;
      aF[i] = *(const bf16x8*)&As[cur][((size_t)r * 4 + (q ^ ((r >> 1) & 3))) * 8];
    }
#pragma unroll
    for (int j = 0; j < 4; j++) {
      int r = wn * 64 + j * 16 + l15;
      bF[j] = *(const bf16x8*)&Bs[cur][((size_t)r * 4 + (q ^ ((r >> 1) & 3))) * 8];
    }
#pragma unroll
    for (int i = 0; i < 4; i++)
#pragma unroll
      for (int j = 0; j < 4; j++)
        acc[i][j] = __builtin_amdgcn_mfma_f32_16x16x32_bf16(aF[i], bF[j], acc[i][j], 0, 0, 0);

    __syncthreads();                     // drains this step's stage + all LDS reads
    cur ^= 1;
  }

  int q = lane >> 4, l15 = lane & 15;
#pragma unroll
  for (int i = 0; i < 4; i++) {
#pragma unroll
    for (int r = 0; r < 4; r++) {
      int rl = wm * 64 + i * 16 + q * 4 + r;
      int grow = m0 + rl;
      if (grow < cnt) {
        int p = moff + grow;
        if (!SECOND) {
          float w = row_weight[p];
#pragma unroll
          for (int j = 0; j < 4; j++) {
            int col = n0 + wn * 64 + j * 16 + l15;
            float v = acc[i][j][r];
            v = (v > 0.f) ? v * v * w : 0.f;
            hidden[(size_t)p * HF + col] = f2bf(v);
          }
        } else {
#pragma unroll
          for (int j = 0; j < 4; j++) {
            int col = n0 + wn * 64 + j * 16 + l15;
            out_slot[(size_t)p * H + col] = acc[i][j][r];
          }
        }
      }
    }
  }
}

// ---------------- combine: out[t] = out_slot[s1] + out_slot[s2] ----------------
__global__ __launch_bounds__(256) void k_combine(const float* __restrict__ out_slot,
                                                 const int* __restrict__ tok_slot,
                                                 float* __restrict__ out) {
  int t = blockIdx.x;
  int s1 = tok_slot[2 * t], s2 = tok_slot[2 * t + 1];
  int c = threadIdx.x * 4;
  float4 a = *(const float4*)(out_slot + (size_t)s1 * H + c);
  float4 b = *(const float4*)(out_slot + (size_t)s2 * H + c);
  float4 o;
  o.x = a.x + b.x; o.y = a.y + b.y; o.z = a.z + b.z; o.w = a.w + b.w;
  *(float4*)(out + (size_t)t * H + c) = o;
}

extern "C" void kernel_launch(void* const* d_in, const int* in_sizes, int n_in,
                              void* d_out, int out_size, void* d_ws, size_t ws_size,
                              hipStream_t stream) {
  const float* x  = (const float*)d_in[0];   // [8192,1024]
  const float* gw = (const float*)d_in[1];   // [1024,8]
  const float* w1 = (const float*)d_in[2];   // [8,1024,4096]
  const float* w2 = (const float*)d_in[3];   // [8,4096,1024]
  float* out = (float*)d_out;

  uint8_t* W = (uint8_t*)d_ws;
  int*   counts    = (int*)(W + 0);
  int*   cursors   = (int*)(W + 64);
  int*   offsets   = (int*)(W + 128);
  int*   topk_e    = (int*)(W + 4096);
  float* topk_w    = (float*)(W + 4096 + 65536);
  int*   tok_slot  = (int*)(W + 4096 + 2 * 65536);
  float* row_weight= (float*)(W + 4096 + 3 * 65536);
  size_t MB = 1ull << 20;
  unsigned short* A_pack = (unsigned short*)(W + 1 * MB);    // ~33.8MB (incl 128-row pad)
  unsigned short* wt1    = (unsigned short*)(W + 35 * MB);   // 64MB
  unsigned short* wt2    = (unsigned short*)(W + 99 * MB);   // 64MB
  unsigned short* hidden = (unsigned short*)(W + 163 * MB);  // ~129.1MB (incl pad) -> 292MB
  float* out_slot = (float*)wt1;  // wt1 is dead after GEMM1; reuse its 64MB for out_slot

  k_init<<<1, 64, 0, stream>>>(counts);
  k_router<<<T_TOK / 4, 256, 0, stream>>>(x, gw, counts, topk_e, topk_w);
  k_scan<<<1, 64, 0, stream>>>(counts, offsets, cursors);
  k_fill<<<T_TOK / 4, 256, 0, stream>>>(x, topk_e, topk_w, offsets, cursors,
                                        tok_slot, row_weight, A_pack);
  // w1: K=1024, N=4096 ; w2: K=4096, N=1024
  k_transpose_cvt<<<dim3(H / 64, HF / 64, NE), 256, 0, stream>>>(w1, wt1, H, HF);
  k_transpose_cvt<<<dim3(HF / 64, H / 64, NE), 256, 0, stream>>>(w2, wt2, HF, H);

  // GEMM1: [cnt_e,1024] @ [1024,4096]^T-layout -> relu^2*w -> hidden (bf16)
  k_gemm<H, false><<<dim3(HF / 128, T_TOK / 128, NE), 256, 0, stream>>>(
      A_pack, wt1, counts, offsets, row_weight, hidden, out_slot, HF);
  // GEMM2: [cnt_e,4096] @ [4096,1024]^T-layout -> out_slot (fp32)
  k_gemm<HF, true><<<dim3(H / 128, T_TOK / 128, NE), 256, 0, stream>>>(
      hidden, wt2, counts, offsets, row_weight, hidden, out_slot, H);
  // combine the two expert contributions per token
  k_combine<<<T_TOK, 256, 0, stream>>>(out_slot, tok_slot, out);
}

// Round 2
// 1188.493 us; speedup vs baseline: 1.0492x; 1.0026x over previous
//
#include <hip/hip_runtime.h>
#include <hip/hip_bf16.h>
#include <stdint.h>

#define T_TOK 8192
#define H     1024
#define HF    4096
#define NE    8
#define NPAIR (2 * T_TOK)
#define ROWCAP (NPAIR + 127)   // last valid (padded) row index in A_pack / hidden

typedef __bf16 bf16x8 __attribute__((ext_vector_type(8)));
typedef float  floatx4 __attribute__((ext_vector_type(4)));

typedef const __attribute__((address_space(1))) uint32_t g_u32;
typedef __attribute__((address_space(3))) uint32_t l_u32;

__device__ __forceinline__ void async_ld16(const void* g, void* l) {
  // LDS dest = wave-uniform base + lane*16; per-lane global address
  __builtin_amdgcn_global_load_lds((g_u32*)g, (l_u32*)l, 16, 0, 0);
}

// raw barrier with scheduling fences; does NOT drain vmcnt (that's the point)
__device__ __forceinline__ void block_bar() {
  __builtin_amdgcn_sched_barrier(0);
  __builtin_amdgcn_s_barrier();
  __builtin_amdgcn_sched_barrier(0);
}

__device__ __forceinline__ unsigned short f2bf(float f) {
  union { float f; uint32_t u; } v; v.f = f;
  uint32_t r = (v.u + 0x7FFFu + ((v.u >> 16) & 1u)) >> 16;
  return (unsigned short)r;
}

// ---------------- init: zero counts ----------------
__global__ void k_init(int* counts) {
  if (threadIdx.x < NE) counts[threadIdx.x] = 0;
}

// ---------------- router: one wave per token ----------------
__global__ __launch_bounds__(256) void k_router(const float* __restrict__ x,
                                                const float* __restrict__ gw,
                                                int* counts, int* topk_e, float* topk_w) {
  int wave = threadIdx.x >> 6, lane = threadIdx.x & 63;
  int t = blockIdx.x * 4 + wave;
  float acc[NE];
#pragma unroll
  for (int e = 0; e < NE; e++) acc[e] = 0.f;
  const float* xr = x + (size_t)t * H;
  for (int k = lane; k < H; k += 64) {
    float xv = xr[k];
    const float* g = gw + (size_t)k * NE;
#pragma unroll
    for (int e = 0; e < NE; e++) acc[e] += xv * g[e];
  }
#pragma unroll
  for (int off = 32; off > 0; off >>= 1) {
#pragma unroll
    for (int e = 0; e < NE; e++) acc[e] += __shfl_xor(acc[e], off, 64);
  }
  if (lane == 0) {
    int e1 = 0;
#pragma unroll
    for (int e = 1; e < NE; e++) if (acc[e] > acc[e1]) e1 = e;
    int e2 = (e1 == 0) ? 1 : 0;
#pragma unroll
    for (int e = 0; e < NE; e++) if (e != e1 && acc[e] > acc[e2]) e2 = e;
    // renormalized top-2 softmax weights: w1 = p1/(p1+p2) = 1/(1+exp(l2-l1))
    float w1 = 1.f / (1.f + expf(acc[e2] - acc[e1]));
    topk_e[2 * t] = e1; topk_e[2 * t + 1] = e2;
    topk_w[2 * t] = w1; topk_w[2 * t + 1] = 1.f - w1;
    atomicAdd(&counts[e1], 1);
    atomicAdd(&counts[e2], 1);
  }
}

// ---------------- scan: offsets + zero cursors ----------------
__global__ void k_scan(const int* counts, int* offsets, int* cursors) {
  if (threadIdx.x == 0) {
    int s = 0;
    for (int e = 0; e < NE; e++) { offsets[e] = s; s += counts[e]; cursors[e] = 0; }
    offsets[NE] = s;
  }
}

// ---------------- fill: slot assignment + gather x -> bf16 packed A ----------------
__global__ __launch_bounds__(256) void k_fill(const float* __restrict__ x,
                                              const int* __restrict__ topk_e,
                                              const float* __restrict__ topk_w,
                                              const int* __restrict__ offsets, int* cursors,
                                              int* tok_slot, float* row_weight,
                                              unsigned short* __restrict__ A_pack) {
  int wave = threadIdx.x >> 6, lane = threadIdx.x & 63;
  int t = blockIdx.x * 4 + wave;
  int s1 = 0, s2 = 0;
  if (lane == 0) {
    int e1 = topk_e[2 * t], e2 = topk_e[2 * t + 1];
    s1 = offsets[e1] + atomicAdd(&cursors[e1], 1);
    s2 = offsets[e2] + atomicAdd(&cursors[e2], 1);
    tok_slot[2 * t] = s1; tok_slot[2 * t + 1] = s2;
    row_weight[s1] = topk_w[2 * t];
    row_weight[s2] = topk_w[2 * t + 1];
  }
  s1 = __shfl(s1, 0, 64);
  s2 = __shfl(s2, 0, 64);
  const float* xr = x + (size_t)t * H;
  unsigned short* d1 = A_pack + (size_t)s1 * H;
  unsigned short* d2 = A_pack + (size_t)s2 * H;
  for (int k = lane * 4; k < H; k += 256) {
    float4 v = *(const float4*)(xr + k);
    ushort4 b;
    b.x = f2bf(v.x); b.y = f2bf(v.y); b.z = f2bf(v.z); b.w = f2bf(v.w);
    *(ushort4*)(d1 + k) = b;
    *(ushort4*)(d2 + k) = b;
  }
}

// ---------------- transpose + cvt: [E][K][N] f32 -> [E][N][K] bf16 ----------------
__global__ __launch_bounds__(256) void k_transpose_cvt(const float* __restrict__ src,
                                                       unsigned short* __restrict__ dst,
                                                       int K, int N) {
  __shared__ unsigned short tile[64][65];
  int e = blockIdx.z;
  int k0 = blockIdx.x * 64, n0 = blockIdx.y * 64;
  const float* S = src + (size_t)e * K * N;
  unsigned short* D = dst + (size_t)e * N * K;
  int tr = threadIdx.x >> 4;
  int tc = (threadIdx.x & 15) * 4;
#pragma unroll
  for (int rr = 0; rr < 64; rr += 16) {
    float4 v = *(const float4*)(S + (size_t)(k0 + tr + rr) * N + n0 + tc);
    tile[tr + rr][tc + 0] = f2bf(v.x);
    tile[tr + rr][tc + 1] = f2bf(v.y);
    tile[tr + rr][tc + 2] = f2bf(v.z);
    tile[tr + rr][tc + 3] = f2bf(v.w);
  }
  __syncthreads();
#pragma unroll
  for (int rr = 0; rr < 64; rr += 16) {
    int i = tr + rr;
    ushort4 o;
    o.x = tile[tc + 0][i]; o.y = tile[tc + 1][i];
    o.z = tile[tc + 2][i]; o.w = tile[tc + 3][i];
    *(ushort4*)(D + (size_t)(n0 + i) * K + k0 + tc) = o;
  }
}

// ---------------- GEMM: 256x256 tile, BK=64, 8 waves (2Mx4N), counted-vmcnt schedule ----
// v3 (this round):
//  * 256x256 / BK=64 / 512 threads / 128 KiB dynamic LDS (2 buffers x (A 32K + B 32K)).
//  * Counted vmcnt pipeline: STAGE(tile t+2 -> buf t&1) issued right after tile t's last
//    phase barrier (buffer just freed); boundary wait is vmcnt(8) (tile t+1 complete,
//    t+2's 8 loads stay in flight) -- NEVER vmcnt(0) in steady state. Raw s_barrier
//    (no implicit vmcnt(0) drain) + sched_barrier(0) fences.
//  * 4 phases per K-tile = (kk, mh): {ds_read frags; setprio(1); 16 MFMA; setprio(0); bar}.
//    24 ds_read_b128 / wave / K-tile (A 16 unique + B 8 unique, B held across mh).
//  * LDS swizzle for 128B row stride: 16B-slot sl ^ (row&7), applied on the pre-swizzled
//    global source of global_load_lds AND the ds_read address (both-sides rule).
//    16 lanes of a fragment read hit 8 distinct slots (2-way aliasing = free).
//  * A-row clamp to ROWCAP for 256-row m-tail (padded rows discarded by grow<cnt).
// SECOND=false: epilogue relu^2 * row_weight -> hidden bf16
// SECOND=true : epilogue -> out_slot[p][col] fp32 (combined later; no atomics)
template <int KD, bool SECOND>
__global__ __launch_bounds__(512, 2) void k_gemm(const unsigned short* __restrict__ A,
                                                 const unsigned short* __restrict__ BT,
                                                 const int* __restrict__ counts,
                                                 const int* __restrict__ offsets,
                                                 const float* __restrict__ row_weight,
                                                 unsigned short* __restrict__ hidden,
                                                 float* __restrict__ out_slot, int Nd) {
  int e = blockIdx.z;
  int cnt = counts[e];
  int nact = (cnt + 255) >> 8;               // active 256-row m-blocks for this expert
  int NX = gridDim.x;
  int bid = blockIdx.y * NX + blockIdx.x;
  int nwg_a = NX * nact;
  if (bid >= nwg_a) return;                  // dead padding blocks (uniform per block)
  // m204 bijective XCD chunk swizzle over the active sub-grid
  int xcd = bid & 7, loc = bid >> 3;
  int q8 = nwg_a >> 3, r8 = nwg_a & 7;
  int swz = (xcd < r8 ? xcd * (q8 + 1) : r8 * (q8 + 1) + (xcd - r8) * q8) + loc;
  int by = swz % nact;                       // m fastest within an XCD chunk ->
  int bx = swz / nact;                       // B n-panel stays resident in that XCD's L2
  int m0 = by * 256;
  int n0 = bx * 256;
  int moff = offsets[e];

  extern __shared__ __align__(16) unsigned short lds[];
  unsigned short* AsL = lds;                 // [2][256*64] bf16
  unsigned short* BsL = lds + 2 * 16384;     // [2][256*64] bf16

  int tid = threadIdx.x, wave = tid >> 6, lane = tid & 63;
  int wm = wave >> 2, wn = wave & 3;         // 2 (M) x 4 (N) wave grid; per-wave out 128x64

  floatx4 acc[8][4] = {};

  const unsigned short* Be = BT + (size_t)e * Nd * KD + (size_t)n0 * KD;

  // stage one 256x64 A-tile + B-tile into buffer `buf` at k-offset k0s.
  // 8 global_load_lds per thread (4 chunks x {A,B}); LDS dest linear, global src
  // pre-swizzled: slot sl of row holds global 8-elem quad (sl ^ (row&7)).
  auto stage = [&](int k0s, int buf) {
#pragma unroll
    for (int c = 0; c < 4; c++) {
      int s_i = c * 512 + tid;               // 16B-slot index 0..2047
      int row = s_i >> 3;                    // 0..255
      int sl  = s_i & 7;                     // slot within 128B row
      int sg  = sl ^ (row & 7);              // global quad (xor swizzle, within row)
      int goff = k0s + sg * 8;
      int ar = moff + m0 + row;
      ar = ar > ROWCAP ? ROWCAP : ar;        // clamp m-tail reads into padded region
      async_ld16(A + (size_t)ar * KD + goff,
                 (void*)(AsL + (size_t)buf * 16384 + (c * 8 + wave) * 512));
      async_ld16(Be + (size_t)row * KD + goff,
                 (void*)(BsL + (size_t)buf * 16384 + (c * 8 + wave) * 512));
    }
  };

  const int NT = KD / 64;
  stage(0, 0);                               // tile 0 -> buf 0
  stage(64, 1);                              // tile 1 -> buf 1 (stays in flight)
  asm volatile("s_waitcnt vmcnt(8)" ::: "memory");   // tile 0 complete
  block_bar();

  int q = lane >> 4, l15 = lane & 15;
  for (int t = 0; t < NT; t++) {
    const unsigned short* Ap = AsL + (size_t)(t & 1) * 16384;
    const unsigned short* Bp = BsL + (size_t)(t & 1) * 16384;
#pragma unroll
    for (int kk = 0; kk < 2; kk++) {
      bf16x8 bF[4];
#pragma unroll
      for (int j = 0; j < 4; j++) {
        int r = wn * 64 + j * 16 + l15;
        bF[j] = *(const bf16x8*)&Bp[(size_t)r * 64 + ((((kk << 2) + q) ^ (r & 7)) * 8)];
      }
#pragma unroll
      for (int mh = 0; mh < 2; mh++) {
        bf16x8 aF[4];
#pragma unroll
        for (int ii = 0; ii < 4; ii++) {
          int r = wm * 128 + mh * 64 + ii * 16 + l15;
          aF[ii] = *(const bf16x8*)&Ap[(size_t)r * 64 + ((((kk << 2) + q) ^ (r & 7)) * 8)];
        }
        __builtin_amdgcn_s_setprio(1);
#pragma unroll
        for (int ii = 0; ii < 4; ii++)
#pragma unroll
          for (int j = 0; j < 4; j++)
            acc[mh * 4 + ii][j] = __builtin_amdgcn_mfma_f32_16x16x32_bf16(
                aF[ii], bF[j], acc[mh * 4 + ii][j], 0, 0, 0);
        __builtin_amdgcn_s_setprio(0);
        block_bar();                         // phase barrier; last one frees buf (t&1)
      }
    }
    if (t + 1 < NT) {
      if (t + 2 < NT) {
        stage((t + 2) * 64, t & 1);          // restage the buffer just consumed
        asm volatile("s_waitcnt vmcnt(8)" ::: "memory");  // tile t+1 done; t+2 in flight
      } else {
        asm volatile("s_waitcnt vmcnt(0)" ::: "memory");  // drain last tile
      }
      block_bar();
    }
  }

  // epilogue: C row = wm*128 + i*16 + q*4 + r ; col = n0 + wn*64 + j*16 + l15
#pragma unroll
  for (int i = 0; i < 8; i++) {
#pragma unroll
    for (int r = 0; r < 4; r++) {
      int rl = wm * 128 + i * 16 + q * 4 + r;
      int grow = m0 + rl;
      if (grow < cnt) {
        int p = moff + grow;
        if (!SECOND) {
          float w = row_weight[p];
#pragma unroll
          for (int j = 0; j < 4; j++) {
            int col = n0 + wn * 64 + j * 16 + l15;
            float v = acc[i][j][r];
            v = (v > 0.f) ? v * v * w : 0.f;
            hidden[(size_t)p * HF + col] = f2bf(v);
          }
        } else {
#pragma unroll
          for (int j = 0; j < 4; j++) {
            int col = n0 + wn * 64 + j * 16 + l15;
            out_slot[(size_t)p * H + col] = acc[i][j][r];
          }
        }
      }
    }
  }
}

// ---------------- combine: out[t] = out_slot[s1] + out_slot[s2] ----------------
__global__ __launch_bounds__(256) void k_combine(const float* __restrict__ out_slot,
                                                 const int* __restrict__ tok_slot,
                                                 float* __restrict__ out) {
  int t = blockIdx.x;
  int s1 = tok_slot[2 * t], s2 = tok_slot[2 * t + 1];
  int c = threadIdx.x * 4;
  float4 a = *(const float4*)(out_slot + (size_t)s1 * H + c);
  float4 b = *(const float4*)(out_slot + (size_t)s2 * H + c);
  float4 o;
  o.x = a.x + b.x; o.y = a.y + b.y; o.z = a.z + b.z; o.w = a.w + b.w;
  *(float4*)(out + (size_t)t * H + c) = o;
}

extern "C" void kernel_launch(void* const* d_in, const int* in_sizes, int n_in,
                              void* d_out, int out_size, void* d_ws, size_t ws_size,
                              hipStream_t stream) {
  const float* x  = (const float*)d_in[0];   // [8192,1024]
  const float* gw = (const float*)d_in[1];   // [1024,8]
  const float* w1 = (const float*)d_in[2];   // [8,1024,4096]
  const float* w2 = (const float*)d_in[3];   // [8,4096,1024]
  float* out = (float*)d_out;

  uint8_t* W = (uint8_t*)d_ws;
  int*   counts    = (int*)(W + 0);
  int*   cursors   = (int*)(W + 64);
  int*   offsets   = (int*)(W + 128);
  int*   topk_e    = (int*)(W + 4096);
  float* topk_w    = (float*)(W + 4096 + 65536);
  int*   tok_slot  = (int*)(W + 4096 + 2 * 65536);
  float* row_weight= (float*)(W + 4096 + 3 * 65536);
  size_t MB = 1ull << 20;
  unsigned short* A_pack = (unsigned short*)(W + 1 * MB);    // ~33.8MB (incl 128-row pad)
  unsigned short* wt1    = (unsigned short*)(W + 35 * MB);   // 64MB
  unsigned short* wt2    = (unsigned short*)(W + 99 * MB);   // 64MB
  unsigned short* hidden = (unsigned short*)(W + 163 * MB);  // ~129.1MB (incl pad) -> 292MB
  float* out_slot = (float*)wt1;  // wt1 is dead after GEMM1; reuse its 64MB for out_slot

  static bool attr_set = false;
  if (!attr_set) {
    (void)hipFuncSetAttribute((const void*)&k_gemm<H, false>,
                              hipFuncAttributeMaxDynamicSharedMemorySize, 131072);
    (void)hipFuncSetAttribute((const void*)&k_gemm<HF, true>,
                              hipFuncAttributeMaxDynamicSharedMemorySize, 131072);
    attr_set = true;
  }

  k_init<<<1, 64, 0, stream>>>(counts);
  k_router<<<T_TOK / 4, 256, 0, stream>>>(x, gw, counts, topk_e, topk_w);
  k_scan<<<1, 64, 0, stream>>>(counts, offsets, cursors);
  k_fill<<<T_TOK / 4, 256, 0, stream>>>(x, topk_e, topk_w, offsets, cursors,
                                        tok_slot, row_weight, A_pack);
  // w1: K=1024, N=4096 ; w2: K=4096, N=1024
  k_transpose_cvt<<<dim3(H / 64, HF / 64, NE), 256, 0, stream>>>(w1, wt1, H, HF);
  k_transpose_cvt<<<dim3(HF / 64, H / 64, NE), 256, 0, stream>>>(w2, wt2, HF, H);

  // GEMM1: [cnt_e,1024] @ [1024,4096]^T-layout -> relu^2*w -> hidden (bf16)
  k_gemm<H, false><<<dim3(HF / 256, 32, NE), 512, 131072, stream>>>(
      A_pack, wt1, counts, offsets, row_weight, hidden, out_slot, HF);
  // GEMM2: [cnt_e,4096] @ [4096,1024]^T-layout -> out_slot (fp32)
  k_gemm<HF, true><<<dim3(H / 256, 32, NE), 512, 131072, stream>>>(
      hidden, wt2, counts, offsets, row_weight, hidden, out_slot, H);
  // combine the two expert contributions per token
  k_combine<<<T_TOK, 256, 0, stream>>>(out_slot, tok_slot, out);
}

// Round 3
// 1121.411 us; speedup vs baseline: 1.1119x; 1.0598x over previous
//
#include <hip/hip_runtime.h>
#include <hip/hip_bf16.h>
#include <stdint.h>

#define T_TOK 8192
#define H     1024
#define HF    4096
#define NE    8
#define NPAIR (2 * T_TOK)
#define ROWCAP (NPAIR + 127)   // last valid (padded) row index in A_pack / hidden

typedef __bf16 bf16x8 __attribute__((ext_vector_type(8)));
typedef float  floatx4 __attribute__((ext_vector_type(4)));

typedef const __attribute__((address_space(1))) uint32_t g_u32;
typedef __attribute__((address_space(3))) uint32_t l_u32;

__device__ __forceinline__ void async_ld16(const void* g, void* l) {
  // LDS dest = wave-uniform base + lane*16; per-lane global address
  __builtin_amdgcn_global_load_lds((g_u32*)g, (l_u32*)l, 16, 0, 0);
}

// raw barrier with scheduling fences; does NOT drain vmcnt (that's the point)
__device__ __forceinline__ void block_bar() {
  __builtin_amdgcn_sched_barrier(0);
  __builtin_amdgcn_s_barrier();
  __builtin_amdgcn_sched_barrier(0);
}

__device__ __forceinline__ unsigned short f2bf(float f) {
  union { float f; uint32_t u; } v; v.f = f;
  uint32_t r = (v.u + 0x7FFFu + ((v.u >> 16) & 1u)) >> 16;
  return (unsigned short)r;
}

// ---------------- init: zero counts ----------------
__global__ void k_init(int* counts) {
  if (threadIdx.x < NE) counts[threadIdx.x] = 0;
}

// ---------------- router: one wave per token ----------------
__global__ __launch_bounds__(256) void k_router(const float* __restrict__ x,
                                                const float* __restrict__ gw,
                                                int* counts, int* topk_e, float* topk_w) {
  int wave = threadIdx.x >> 6, lane = threadIdx.x & 63;
  int t = blockIdx.x * 4 + wave;
  float acc[NE];
#pragma unroll
  for (int e = 0; e < NE; e++) acc[e] = 0.f;
  const float* xr = x + (size_t)t * H;
  for (int k = lane; k < H; k += 64) {
    float xv = xr[k];
    const float* g = gw + (size_t)k * NE;
#pragma unroll
    for (int e = 0; e < NE; e++) acc[e] += xv * g[e];
  }
#pragma unroll
  for (int off = 32; off > 0; off >>= 1) {
#pragma unroll
    for (int e = 0; e < NE; e++) acc[e] += __shfl_xor(acc[e], off, 64);
  }
  if (lane == 0) {
    int e1 = 0;
#pragma unroll
    for (int e = 1; e < NE; e++) if (acc[e] > acc[e1]) e1 = e;
    int e2 = (e1 == 0) ? 1 : 0;
#pragma unroll
    for (int e = 0; e < NE; e++) if (e != e1 && acc[e] > acc[e2]) e2 = e;
    // renormalized top-2 softmax weights: w1 = p1/(p1+p2) = 1/(1+exp(l2-l1))
    float w1 = 1.f / (1.f + expf(acc[e2] - acc[e1]));
    topk_e[2 * t] = e1; topk_e[2 * t + 1] = e2;
    topk_w[2 * t] = w1; topk_w[2 * t + 1] = 1.f - w1;
    atomicAdd(&counts[e1], 1);
    atomicAdd(&counts[e2], 1);
  }
}

// ---------------- scan: offsets + zero cursors ----------------
__global__ void k_scan(const int* counts, int* offsets, int* cursors) {
  if (threadIdx.x == 0) {
    int s = 0;
    for (int e = 0; e < NE; e++) { offsets[e] = s; s += counts[e]; cursors[e] = 0; }
    offsets[NE] = s;
  }
}

// ---------------- fill: slot assignment + gather x -> bf16 packed A ----------------
__global__ __launch_bounds__(256) void k_fill(const float* __restrict__ x,
                                              const int* __restrict__ topk_e,
                                              const float* __restrict__ topk_w,
                                              const int* __restrict__ offsets, int* cursors,
                                              int* tok_slot, float* row_weight,
                                              unsigned short* __restrict__ A_pack) {
  int wave = threadIdx.x >> 6, lane = threadIdx.x & 63;
  int t = blockIdx.x * 4 + wave;
  int s1 = 0, s2 = 0;
  if (lane == 0) {
    int e1 = topk_e[2 * t], e2 = topk_e[2 * t + 1];
    s1 = offsets[e1] + atomicAdd(&cursors[e1], 1);
    s2 = offsets[e2] + atomicAdd(&cursors[e2], 1);
    tok_slot[2 * t] = s1; tok_slot[2 * t + 1] = s2;
    row_weight[s1] = topk_w[2 * t];
    row_weight[s2] = topk_w[2 * t + 1];
  }
  s1 = __shfl(s1, 0, 64);
  s2 = __shfl(s2, 0, 64);
  const float* xr = x + (size_t)t * H;
  unsigned short* d1 = A_pack + (size_t)s1 * H;
  unsigned short* d2 = A_pack + (size_t)s2 * H;
  for (int k = lane * 4; k < H; k += 256) {
    float4 v = *(const float4*)(xr + k);
    ushort4 b;
    b.x = f2bf(v.x); b.y = f2bf(v.y); b.z = f2bf(v.z); b.w = f2bf(v.w);
    *(ushort4*)(d1 + k) = b;
    *(ushort4*)(d2 + k) = b;
  }
}

// ---------------- transpose + cvt: [E][K][N] f32 -> [E][N][K] bf16 ----------------
__global__ __launch_bounds__(256) void k_transpose_cvt(const float* __restrict__ src,
                                                       unsigned short* __restrict__ dst,
                                                       int K, int N) {
  __shared__ unsigned short tile[64][65];
  int e = blockIdx.z;
  int k0 = blockIdx.x * 64, n0 = blockIdx.y * 64;
  const float* S = src + (size_t)e * K * N;
  unsigned short* D = dst + (size_t)e * N * K;
  int tr = threadIdx.x >> 4;
  int tc = (threadIdx.x & 15) * 4;
#pragma unroll
  for (int rr = 0; rr < 64; rr += 16) {
    float4 v = *(const float4*)(S + (size_t)(k0 + tr + rr) * N + n0 + tc);
    tile[tr + rr][tc + 0] = f2bf(v.x);
    tile[tr + rr][tc + 1] = f2bf(v.y);
    tile[tr + rr][tc + 2] = f2bf(v.z);
    tile[tr + rr][tc + 3] = f2bf(v.w);
  }
  __syncthreads();
#pragma unroll
  for (int rr = 0; rr < 64; rr += 16) {
    int i = tr + rr;
    ushort4 o;
    o.x = tile[tc + 0][i]; o.y = tile[tc + 1][i];
    o.z = tile[tc + 2][i]; o.w = tile[tc + 3][i];
    *(ushort4*)(D + (size_t)(n0 + i) * K + k0 + tc) = o;
  }
}

// ---------------- GEMM: 256x256 tile, BK=32, 8 waves, 3-buffer streamed pipeline --------
// v4 (this round):
//  * 3 LDS buffers x (A 16K + B 16K) = 96 KiB, BK=32. While computing tile t (buf t%3),
//    tile t+2's 4 loads are issued SPREAD across tile t's two phases (2/phase) into buf
//    (t+2)%3, which has been free since the end of tile t-1 -> streamed issue, prefetch
//    distance ~2 tile-periods (vs r2's 1-tile burst).
//  * ONE barrier per K-tile (after vmcnt(4)): the minimum for buffer rotation. No
//    per-phase barriers -> waves skew and cover each other's stalls (intra-block TLP;
//    a 2nd block/CU is impossible: acc[8][4]=128 VGPR/wave caps at 2 waves/SIMD).
//  * vmcnt(4) at the boundary: tile t+1's 4 loads done, t+2's 4 stay in flight. Never
//    vmcnt(0) in steady state.
//  * Pair-line LDS swizzle for 64-B rows (BK=32): two rows per 128-B line, 16B-slot =
//    ((row&1)*4+q) ^ ((row>>1)&7). Bijective; fragment ds_read_b128 is 2-way (free,
//    banks = f(slot) only since line stride = 128 B = 32 banks); staging source stays
//    64-B-coalesced. Inverse swizzle applied on the global source (both-sides rule).
// SECOND=false: epilogue relu^2 * row_weight -> hidden bf16
// SECOND=true : epilogue -> out_slot[p][col] fp32 (combined later; no atomics)
template <int KD, bool SECOND>
__global__ __launch_bounds__(512, 2) void k_gemm(const unsigned short* __restrict__ A,
                                                 const unsigned short* __restrict__ BT,
                                                 const int* __restrict__ counts,
                                                 const int* __restrict__ offsets,
                                                 const float* __restrict__ row_weight,
                                                 unsigned short* __restrict__ hidden,
                                                 float* __restrict__ out_slot, int Nd) {
  int e = blockIdx.z;
  int cnt = counts[e];
  int nact = (cnt + 255) >> 8;               // active 256-row m-blocks for this expert
  int NX = gridDim.x;
  int bid = blockIdx.y * NX + blockIdx.x;
  int nwg_a = NX * nact;
  if (bid >= nwg_a) return;                  // dead padding blocks (uniform per block)
  // m204 bijective XCD chunk swizzle over the active sub-grid
  int xcd = bid & 7, loc = bid >> 3;
  int q8 = nwg_a >> 3, r8 = nwg_a & 7;
  int swz = (xcd < r8 ? xcd * (q8 + 1) : r8 * (q8 + 1) + (xcd - r8) * q8) + loc;
  int by = swz % nact;                       // m fastest within an XCD chunk ->
  int bx = swz / nact;                       // B n-panel stays resident in that XCD's L2
  int m0 = by * 256;
  int n0 = bx * 256;
  int moff = offsets[e];

  extern __shared__ __align__(16) unsigned short lds[];
  // buf b (b=0..2): A at ushort-offset b*16384, B at b*16384 + 8192

  int tid = threadIdx.x, wave = tid >> 6, lane = tid & 63;
  int wm = wave >> 2, wn = wave & 3;         // 2 (M) x 4 (N) wave grid; per-wave out 128x64

  floatx4 acc[8][4] = {};

  const unsigned short* Be = BT + (size_t)e * Nd * KD + (size_t)n0 * KD;

  // stage half (0 = A 256x32, 1 = B 256x32) of K-tile at element offset k0s into buf.
  // 2 global_load_lds per thread per half. LDS dest linear in slot index s_i; global
  // source pre-swizzled: slot s_i holds (row = 2*line+(v>>2), quad = v&3), v = sl^(line&7).
  auto stage_half = [&](int k0s, int buf, int half) {
#pragma unroll
    for (int c = 0; c < 2; c++) {
      int s_i = c * 512 + tid;               // 16B-slot 0..1023
      int line = s_i >> 3, sl = s_i & 7;
      int v = sl ^ (line & 7);
      int row = line * 2 + (v >> 2);         // 0..255
      int goff = k0s + (v & 3) * 8;
      unsigned short* dst = lds + (size_t)buf * 16384 + (size_t)half * 8192 +
                            (size_t)(c * 8 + wave) * 512;
      if (half == 0) {
        int ar = moff + m0 + row;
        ar = ar > ROWCAP ? ROWCAP : ar;      // clamp m-tail reads into padded region
        async_ld16(A + (size_t)ar * KD + goff, (void*)dst);
      } else {
        async_ld16(Be + (size_t)row * KD + goff, (void*)dst);
      }
    }
  };

  // swizzled ushort index of (row r, k-quad q) within a 256x32 LDS matrix
  auto sidx = [&](int r, int q) {
    return (size_t)(((r >> 1) * 8 + ((((r & 1) << 2) | q) ^ ((r >> 1) & 7))) * 8);
  };

  const int NT = KD / 32;
  stage_half(0, 0, 0);  stage_half(0, 0, 1);     // tile 0 -> buf 0
  stage_half(32, 1, 0); stage_half(32, 1, 1);    // tile 1 -> buf 1 (stays in flight)
  asm volatile("s_waitcnt vmcnt(4)" ::: "memory");   // tile 0 complete
  block_bar();

  int q = lane >> 4, l15 = lane & 15;
  int cur = 0, pb = 2;                       // pb = (t+2)%3
  for (int t = 0; t < NT; t++) {
    const unsigned short* Ap = lds + (size_t)cur * 16384;
    const unsigned short* Bp = Ap + 8192;
    bool pf = (t + 2 < NT);
    int k2 = (t + 2) * 32;

    // ---- phase 0: B frags + A-lower frags, stage A-half of tile t+2 ----
    bf16x8 bF[4];
#pragma unroll
    for (int j = 0; j < 4; j++) {
      int r = wn * 64 + j * 16 + l15;
      bF[j] = *(const bf16x8*)&Bp[sidx(r, q)];
    }
    bf16x8 aF[4];
#pragma unroll
    for (int i = 0; i < 4; i++) {
      int r = wm * 128 + i * 16 + l15;
      aF[i] = *(const bf16x8*)&Ap[sidx(r, q)];
    }
    if (pf) stage_half(k2, pb, 0);
    __builtin_amdgcn_s_setprio(1);
#pragma unroll
    for (int i = 0; i < 4; i++)
#pragma unroll
      for (int j = 0; j < 4; j++)
        acc[i][j] = __builtin_amdgcn_mfma_f32_16x16x32_bf16(aF[i], bF[j], acc[i][j], 0, 0, 0);
    __builtin_amdgcn_s_setprio(0);

    // ---- phase 1: A-upper frags, stage B-half of tile t+2 ----
    bf16x8 aG[4];
#pragma unroll
    for (int i = 0; i < 4; i++) {
      int r = wm * 128 + 64 + i * 16 + l15;
      aG[i] = *(const bf16x8*)&Ap[sidx(r, q)];
    }
    if (pf) stage_half(k2, pb, 1);
    __builtin_amdgcn_s_setprio(1);
#pragma unroll
    for (int i = 0; i < 4; i++)
#pragma unroll
      for (int j = 0; j < 4; j++)
        acc[4 + i][j] = __builtin_amdgcn_mfma_f32_16x16x32_bf16(aG[i], bF[j], acc[4 + i][j], 0, 0, 0);
    __builtin_amdgcn_s_setprio(0);

    // ---- boundary: tile t+1 must be resident; t+2 stays in flight ----
    if (t + 1 < NT) {
      if (pf) asm volatile("s_waitcnt vmcnt(4)" ::: "memory");
      else    asm volatile("s_waitcnt vmcnt(0)" ::: "memory");
      block_bar();
    }
    cur = (cur == 2) ? 0 : cur + 1;
    pb  = (pb == 2) ? 0 : pb + 1;
  }

  // epilogue: C row = wm*128 + i*16 + q*4 + r ; col = n0 + wn*64 + j*16 + l15
#pragma unroll
  for (int i = 0; i < 8; i++) {
#pragma unroll
    for (int r = 0; r < 4; r++) {
      int rl = wm * 128 + i * 16 + q * 4 + r;
      int grow = m0 + rl;
      if (grow < cnt) {
        int p = moff + grow;
        if (!SECOND) {
          float w = row_weight[p];
#pragma unroll
          for (int j = 0; j < 4; j++) {
            int col = n0 + wn * 64 + j * 16 + l15;
            float v = acc[i][j][r];
            v = (v > 0.f) ? v * v * w : 0.f;
            hidden[(size_t)p * HF + col] = f2bf(v);
          }
        } else {
#pragma unroll
          for (int j = 0; j < 4; j++) {
            int col = n0 + wn * 64 + j * 16 + l15;
            out_slot[(size_t)p * H + col] = acc[i][j][r];
          }
        }
      }
    }
  }
}

// ---------------- combine: out[t] = out_slot[s1] + out_slot[s2] ----------------
__global__ __launch_bounds__(256) void k_combine(const float* __restrict__ out_slot,
                                                 const int* __restrict__ tok_slot,
                                                 float* __restrict__ out) {
  int t = blockIdx.x;
  int s1 = tok_slot[2 * t], s2 = tok_slot[2 * t + 1];
  int c = threadIdx.x * 4;
  float4 a = *(const float4*)(out_slot + (size_t)s1 * H + c);
  float4 b = *(const float4*)(out_slot + (size_t)s2 * H + c);
  float4 o;
  o.x = a.x + b.x; o.y = a.y + b.y; o.z = a.z + b.z; o.w = a.w + b.w;
  *(float4*)(out + (size_t)t * H + c) = o;
}

extern "C" void kernel_launch(void* const* d_in, const int* in_sizes, int n_in,
                              void* d_out, int out_size, void* d_ws, size_t ws_size,
                              hipStream_t stream) {
  const float* x  = (const float*)d_in[0];   // [8192,1024]
  const float* gw = (const float*)d_in[1];   // [1024,8]
  const float* w1 = (const float*)d_in[2];   // [8,1024,4096]
  const float* w2 = (const float*)d_in[3];   // [8,4096,1024]
  float* out = (float*)d_out;

  uint8_t* W = (uint8_t*)d_ws;
  int*   counts    = (int*)(W + 0);
  int*   cursors   = (int*)(W + 64);
  int*   offsets   = (int*)(W + 128);
  int*   topk_e    = (int*)(W + 4096);
  float* topk_w    = (float*)(W + 4096 + 65536);
  int*   tok_slot  = (int*)(W + 4096 + 2 * 65536);
  float* row_weight= (float*)(W + 4096 + 3 * 65536);
  size_t MB = 1ull << 20;
  unsigned short* A_pack = (unsigned short*)(W + 1 * MB);    // ~33.8MB (incl 128-row pad)
  unsigned short* wt1    = (unsigned short*)(W + 35 * MB);   // 64MB
  unsigned short* wt2    = (unsigned short*)(W + 99 * MB);   // 64MB
  unsigned short* hidden = (unsigned short*)(W + 163 * MB);  // ~129.1MB (incl pad) -> 292MB
  float* out_slot = (float*)wt1;  // wt1 is dead after GEMM1; reuse its 64MB for out_slot

  static bool attr_set = false;
  if (!attr_set) {
    (void)hipFuncSetAttribute((const void*)&k_gemm<H, false>,
                              hipFuncAttributeMaxDynamicSharedMemorySize, 98304);
    (void)hipFuncSetAttribute((const void*)&k_gemm<HF, true>,
                              hipFuncAttributeMaxDynamicSharedMemorySize, 98304);
    attr_set = true;
  }

  k_init<<<1, 64, 0, stream>>>(counts);
  k_router<<<T_TOK / 4, 256, 0, stream>>>(x, gw, counts, topk_e, topk_w);
  k_scan<<<1, 64, 0, stream>>>(counts, offsets, cursors);
  k_fill<<<T_TOK / 4, 256, 0, stream>>>(x, topk_e, topk_w, offsets, cursors,
                                        tok_slot, row_weight, A_pack);
  // w1: K=1024, N=4096 ; w2: K=4096, N=1024
  k_transpose_cvt<<<dim3(H / 64, HF / 64, NE), 256, 0, stream>>>(w1, wt1, H, HF);
  k_transpose_cvt<<<dim3(HF / 64, H / 64, NE), 256, 0, stream>>>(w2, wt2, HF, H);

  // GEMM1: [cnt_e,1024] @ [1024,4096]^T-layout -> relu^2*w -> hidden (bf16)
  k_gemm<H, false><<<dim3(HF / 256, 32, NE), 512, 98304, stream>>>(
      A_pack, wt1, counts, offsets, row_weight, hidden, out_slot, HF);
  // GEMM2: [cnt_e,4096] @ [4096,1024]^T-layout -> out_slot (fp32)
  k_gemm<HF, true><<<dim3(H / 256, 32, NE), 512, 98304, stream>>>(
      hidden, wt2, counts, offsets, row_weight, hidden, out_slot, H);
  // combine the two expert contributions per token
  k_combine<<<T_TOK, 256, 0, stream>>>(out_slot, tok_slot, out);
}